// Round 3
// baseline (1292.893 us; speedup 1.0000x reference)
//
#include <hip/hip_runtime.h>

typedef unsigned short u16;
typedef __bf16 bf16x8 __attribute__((ext_vector_type(8)));
typedef float floatx4 __attribute__((ext_vector_type(4)));

#define NE 800000
#define NN 50000

__device__ __forceinline__ float b2f(unsigned u) { return __uint_as_float(u << 16); }
__device__ __forceinline__ u16 f2b(float f) {
  unsigned x = __float_as_uint(f);
  x += 0x7fffu + ((x >> 16) & 1u);
  return (u16)(x >> 16);
}

// ---------------- dtype sniffer: flag=1 if float inputs are fp32, 0 if bf16 ----------------
// fp32 N(0,1): biased exponent of each word in ~[90,141]. bf16 pair viewed as u32:
// bits[30:23] = sign|exp[7:1] of the odd bf16 -> ~[52,64] or [183,192]. Disjoint.
__global__ void k_sniff(const unsigned* __restrict__ x, int* __restrict__ flag) {
  if (blockIdx.x == 0 && threadIdx.x == 0) {
    int votes = 0;
    for (int i = 0; i < 256; ++i) {
      unsigned e = (x[i] >> 23) & 0xffu;
      votes += (e >= 90u && e <= 141u) ? 1 : 0;
    }
    flag[0] = (votes >= 128) ? 1 : 0;
  }
}

// ---------------- preprocessing ----------------
// DI layout (ints, later rsqrt floats in place):
// [0)=in_follows(user) [50000)=in_ratedby(user) [100000)=in_rates(item)
// [150000)=out_follows(user) [200000)=out_rates(user) [250000)=out_ratedby(item)
__global__ void k_degrees(const int* __restrict__ s0, const int* __restrict__ d0,
                          const int* __restrict__ s1, const int* __restrict__ d1,
                          const int* __restrict__ s2, const int* __restrict__ d2,
                          int* __restrict__ DI) {
  int t = blockIdx.x * 256 + threadIdx.x;
  if (t < NE) {
    atomicAdd(&DI[d0[t]], 1);
    atomicAdd(&DI[150000 + s0[t]], 1);
  } else if (t < 2 * NE) {
    int e = t - NE;
    atomicAdd(&DI[50000 + d1[e]], 1);
    atomicAdd(&DI[250000 + s1[e]], 1);
  } else if (t < 3 * NE) {
    int e = t - 2 * NE;
    atomicAdd(&DI[100000 + d2[e]], 1);
    atomicAdd(&DI[200000 + s2[e]], 1);
  }
}

// exclusive prefix sum over 150000 counts -> offs[0..150000], single block
__global__ __launch_bounds__(1024) void k_scan(const int* __restrict__ cnt,
                                               int* __restrict__ offs) {
  __shared__ int tmp[1024];
  __shared__ int carry;
  int t = threadIdx.x;
  if (t == 0) carry = 0;
  __syncthreads();
  for (int base = 0; base < 150000; base += 1024) {
    int i = base + t;
    int c = (i < 150000) ? cnt[i] : 0;
    tmp[t] = c;
    __syncthreads();
    for (int off = 1; off < 1024; off <<= 1) {
      int v = (t >= off) ? tmp[t - off] : 0;
      __syncthreads();
      tmp[t] += v;
      __syncthreads();
    }
    if (i < 150000) offs[i] = carry + tmp[t] - c;
    __syncthreads();
    if (t == 1023) carry += tmp[1023];
    __syncthreads();
  }
  if (t == 0) offs[150000] = carry;
}

__global__ void k_rsq(int* __restrict__ DI, int n) {
  int i = blockIdx.x * 256 + threadIdx.x;
  if (i < n) {
    float v = (float)DI[i];
    ((float*)DI)[i] = rsqrtf(fmaxf(v, 1.f));
  }
}

__global__ void k_scatter(const int* __restrict__ src, const int* __restrict__ dst,
                          const int* __restrict__ offsR, int* __restrict__ curR,
                          int* __restrict__ csr) {
  int e = blockIdx.x * 256 + threadIdx.x;
  if (e < NE) {
    int d = dst[e];
    int pos = atomicAdd(&curR[d], 1);
    csr[offsR[d] + pos] = src[e];
  }
}

// dst[n*K+k] = f2b(src[k*N+n]); src dtype per flag
__global__ void k_tpose(const void* __restrict__ src, u16* __restrict__ dst, int K, int N,
                        const int* __restrict__ flagp) {
  int i = blockIdx.x * 256 + threadIdx.x;
  int f = flagp[0];
  if (i < K * N) {
    int n = i / K, k = i - n * K;
    float v = f ? ((const float*)src)[k * N + n] : b2f(((const u16*)src)[k * N + n]);
    dst[i] = f2b(v);
  }
}

// biases -> fp32 canonical, 6 arrays at out[a*256 .. ]
__global__ void k_cvtbias(const void* b0, const void* b1, const void* b2,
                          const void* b3, const void* b4, const void* b5,
                          float* __restrict__ out, const int* __restrict__ flagp) {
  int t = threadIdx.x;
  int f = flagp[0];
  const void* ps[6] = {b0, b1, b2, b3, b4, b5};
  const int len[6] = {256, 256, 256, 128, 128, 128};
  for (int a = 0; a < 6; ++a) {
    if (t < len[a]) {
      float v = f ? ((const float*)ps[a])[t] : b2f(((const u16*)ps[a])[t]);
      out[a * 256 + t] = v;
    }
  }
}

// ---------------- GEMM: C[M,Ntot] = A[M,256] @ Bt[Ntot,256]^T, epilogue row-scale ----------------
// A dtype per flagp (nullptr => bf16). Bt/C always bf16. fp32 MFMA accumulate.
__global__ __launch_bounds__(256) void k_gemm(
    const void* __restrict__ A, const u16* __restrict__ Bt, u16* __restrict__ C,
    int M, int Ntot, const float* __restrict__ rs0, const float* __restrict__ rs1, int splitN,
    const int* __restrict__ flagp) {
  __shared__ alignas(16) u16 As[128 * 64];
  __shared__ alignas(16) u16 Bs[128 * 64];
  const int af32 = flagp ? flagp[0] : 0;
  const int tid = threadIdx.x;
  const int mBase = blockIdx.x * 128;
  const int nBase = blockIdx.y * 128;
  const int w = tid >> 6, lane = tid & 63;
  const int wm = w & 1, wn = w >> 1;
  const int lr = lane & 15, quad = lane >> 4;
  floatx4 acc[4][4] = {};
  for (int kb = 0; kb < 256; kb += 64) {
    uint4 va[4], vb[4];
#pragma unroll
    for (int c = 0; c < 4; ++c) {
      int idx = c * 256 + tid;       // 16B(bf16) chunk id; tile 128 rows x 64 cols
      int row = idx >> 3;
      int col8 = (idx & 7) * 8;
      int gr = mBase + row; if (gr > M - 1) gr = M - 1;   // clamp; masked at store
      if (af32) {
        const float* ap = (const float*)A + (size_t)gr * 256 + kb + col8;
        float4 f0 = *(const float4*)ap;
        float4 f1 = *(const float4*)(ap + 4);
        va[c] = make_uint4(
            (unsigned)f2b(f0.x) | ((unsigned)f2b(f0.y) << 16),
            (unsigned)f2b(f0.z) | ((unsigned)f2b(f0.w) << 16),
            (unsigned)f2b(f1.x) | ((unsigned)f2b(f1.y) << 16),
            (unsigned)f2b(f1.z) | ((unsigned)f2b(f1.w) << 16));
      } else {
        va[c] = *(const uint4*)((const u16*)A + (size_t)gr * 256 + kb + col8);
      }
      vb[c] = *(const uint4*)(Bt + (size_t)(nBase + row) * 256 + kb + col8);
    }
#pragma unroll
    for (int c = 0; c < 4; ++c) {
      int idx = c * 256 + tid;
      *(uint4*)(&As[idx * 8]) = va[c];
      *(uint4*)(&Bs[idx * 8]) = vb[c];
    }
    __syncthreads();
#pragma unroll
    for (int ks = 0; ks < 2; ++ks) {
      bf16x8 fa[4], fb[4];
#pragma unroll
      for (int m = 0; m < 4; ++m)
        fa[m] = *(const bf16x8*)(&As[(wm * 64 + m * 16 + lr) * 64 + ks * 32 + quad * 8]);
#pragma unroll
      for (int n = 0; n < 4; ++n)
        fb[n] = *(const bf16x8*)(&Bs[(wn * 64 + n * 16 + lr) * 64 + ks * 32 + quad * 8]);
#pragma unroll
      for (int m = 0; m < 4; ++m)
#pragma unroll
        for (int n = 0; n < 4; ++n)
          acc[m][n] = __builtin_amdgcn_mfma_f32_16x16x32_bf16(fa[m], fb[n], acc[m][n], 0, 0, 0);
    }
    __syncthreads();
  }
  // C/D layout: col = lane&15, row = quad*4 + reg  [m89-verified]
#pragma unroll
  for (int n = 0; n < 4; ++n) {
    int cg = nBase + wn * 64 + n * 16 + lr;
    const float* rs = (cg < splitN) ? rs0 : rs1;
#pragma unroll
    for (int m = 0; m < 4; ++m) {
      int rb_ = mBase + wm * 64 + m * 16 + quad * 4;
#pragma unroll
      for (int r = 0; r < 4; ++r) {
        int rg = rb_ + r;
        if (rg < M) C[(size_t)rg * Ntot + cg] = f2b(acc[m][n][r] * rs[rg]);
      }
    }
  }
}

// ---------------- SpMM (CSR by dst), fp32 accumulate ----------------
template <int VEC>
__device__ __forceinline__ void addv(float* acc, const u16* p) {
  if constexpr (VEC == 4) {
    uint2 v = *(const uint2*)p;
    acc[0] += b2f(v.x & 0xffffu); acc[1] += b2f(v.x >> 16);
    acc[2] += b2f(v.y & 0xffffu); acc[3] += b2f(v.y >> 16);
  } else {
    unsigned v = *(const unsigned*)p;
    acc[0] += b2f(v & 0xffffu); acc[1] += b2f(v >> 16);
  }
}

__device__ __forceinline__ int clampi(int s) {
  return (s < 0) ? 0 : (s > NN - 1 ? NN - 1 : s);
}

// two relations: out = maybeRELU( 0.5*(aggA*rsA + bA + aggB*rsB + bB) )
// store dtype per flagp (nullptr => bf16)
template <int VEC, bool RELU>
__global__ __launch_bounds__(64) void k_spmm2(
    const u16* __restrict__ fA, int sA, int oA,
    const u16* __restrict__ fB, int sB, int oB,
    const int* __restrict__ csr, const int* __restrict__ offs, int baseA, int baseB,
    const float* __restrict__ rsA, const float* __restrict__ rsB,
    const float* __restrict__ bA, const float* __restrict__ bB,
    void* __restrict__ outv, size_t outBase, int sOut, const int* __restrict__ flagp) {
  int d = blockIdx.x, lane = threadIdx.x;
  int f32o = flagp ? flagp[0] : 0;
  float accA[VEC] = {}, accB[VEC] = {};
  int st = offs[baseA + d], en = offs[baseA + d + 1];
  for (int e = st; e < en; ++e)
    addv<VEC>(accA, fA + (size_t)clampi(csr[e]) * sA + oA + lane * VEC);
  st = offs[baseB + d]; en = offs[baseB + d + 1];
  for (int e = st; e < en; ++e)
    addv<VEC>(accB, fB + (size_t)clampi(csr[e]) * sB + oB + lane * VEC);
  float ra = rsA[d], rb = rsB[d];
  size_t o = outBase + (size_t)d * sOut + lane * VEC;
#pragma unroll
  for (int v = 0; v < VEC; ++v) {
    float x = 0.5f * (accA[v] * ra + bA[lane * VEC + v] + accB[v] * rb + bB[lane * VEC + v]);
    if (RELU) x = fmaxf(x, 0.f);
    if (f32o) ((float*)outv)[o + v] = x;
    else      ((u16*)outv)[o + v] = f2b(x);
  }
}

// single relation
template <int VEC, bool RELU>
__global__ __launch_bounds__(64) void k_spmm1(
    const u16* __restrict__ fA, int sA, int oA,
    const int* __restrict__ csr, const int* __restrict__ offs, int baseA,
    const float* __restrict__ rsA, const float* __restrict__ bA,
    void* __restrict__ outv, size_t outBase, int sOut, const int* __restrict__ flagp) {
  int d = blockIdx.x, lane = threadIdx.x;
  int f32o = flagp ? flagp[0] : 0;
  float accA[VEC] = {};
  int st = offs[baseA + d], en = offs[baseA + d + 1];
  for (int e = st; e < en; ++e)
    addv<VEC>(accA, fA + (size_t)clampi(csr[e]) * sA + oA + lane * VEC);
  float ra = rsA[d];
  size_t o = outBase + (size_t)d * sOut + lane * VEC;
#pragma unroll
  for (int v = 0; v < VEC; ++v) {
    float x = accA[v] * ra + bA[lane * VEC + v];
    if (RELU) x = fmaxf(x, 0.f);
    if (f32o) ((float*)outv)[o + v] = x;
    else      ((u16*)outv)[o + v] = f2b(x);
  }
}

extern "C" void kernel_launch(void* const* d_in, const int* in_sizes, int n_in,
                              void* d_out, int out_size, void* d_ws, size_t ws_size,
                              hipStream_t stream) {
  (void)in_sizes; (void)n_in; (void)out_size;
  const void* x_user = d_in[0];
  const void* x_item = d_in[1];
  const void* W1f  = d_in[2];  const void* b1f  = d_in[3];
  const void* W1rt = d_in[4];  const void* b1rt = d_in[5];
  const void* W1rb = d_in[6];  const void* b1rb = d_in[7];
  const void* W2f  = d_in[8];  const void* b2fo = d_in[9];
  const void* W2rt = d_in[10]; const void* b2rt = d_in[11];
  const void* W2rb = d_in[12]; const void* b2rb = d_in[13];
  const int* srcF  = (const int*)d_in[14]; const int* dstF  = (const int*)d_in[15];
  const int* srcR  = (const int*)d_in[16]; const int* dstR  = (const int*)d_in[17];
  const int* srcRB = (const int*)d_in[18]; const int* dstRB = (const int*)d_in[19];

  // ---- workspace layout (bytes) ----
  // DI/R   : [0, 1200000)           300000 i32 -> f32 in place
  // cursor : [1200000, 1800000)     150000 i32; REUSED after scatters for fp32 biases (6x256 f32)
  // flag   : [1800000, 1800004)
  // offs   : [1800064, 2400068)     150001 i32
  // csr    : [2400128, 12000128)    2400000 i32
  // Bt1u/Bt1i/Bt2u/Bt2i bf16        [12000128, 12589952)
  // featA  : [12589952, 63789952)   [50000,512] bf16 (layer2: [50000,256] + feat2rb)
  // featB  : [63789952, 89389952)   [50000,256]
  // h_u    : [89389952, 114989952)  [50000,256]
  if (ws_size < 114989952u) return;  // fail loudly (output stays wrong), don't corrupt

  char* ws = (char*)d_ws;
  int*   DI     = (int*)ws;
  float* R      = (float*)ws;
  int*   cursor = (int*)(ws + 1200000);
  float* BF     = (float*)(ws + 1200000);   // biases, written after scatters
  int*   flag   = (int*)(ws + 1800000);
  int*   offs   = (int*)(ws + 1800064);
  int*   csr    = (int*)(ws + 2400128);
  u16*   Bt1u   = (u16*)(ws + 12000128);
  u16*   Bt1i   = (u16*)(ws + 12262272);
  u16*   Bt2u   = (u16*)(ws + 12393344);
  u16*   Bt2i   = (u16*)(ws + 12524416);
  u16*   featA  = (u16*)(ws + 12589952);
  u16*   featB  = (u16*)(ws + 63789952);
  u16*   h_u    = (u16*)(ws + 89389952);
  u16*   h_i    = featB;
  u16*   feat2rb = featA + (size_t)50000 * 256;

  hipMemsetAsync(ws, 0, 1800000, stream);            // degrees + cursors
  hipMemsetAsync(ws + 2400128, 0, 9600000, stream);  // csr (gaps -> node 0, finite)
  k_sniff<<<1, 64, 0, stream>>>((const unsigned*)x_user, flag);
  k_degrees<<<(3 * NE + 255) / 256, 256, 0, stream>>>(srcF, dstF, srcRB, dstRB, srcR, dstR, DI);
  k_scan<<<1, 1024, 0, stream>>>(DI, offs);
  k_rsq<<<(300000 + 255) / 256, 256, 0, stream>>>(DI, 300000);
  k_scatter<<<(NE + 255) / 256, 256, 0, stream>>>(srcF, dstF, offs, cursor, csr);
  k_scatter<<<(NE + 255) / 256, 256, 0, stream>>>(srcRB, dstRB, offs + 50000, cursor + 50000, csr);
  k_scatter<<<(NE + 255) / 256, 256, 0, stream>>>(srcR, dstR, offs + 100000, cursor + 100000, csr);
  k_cvtbias<<<1, 256, 0, stream>>>(b1f, b1rb, b1rt, b2fo, b2rb, b2rt, BF, flag);
  k_tpose<<<256, 256, 0, stream>>>(W1f, Bt1u, 256, 256, flag);
  k_tpose<<<256, 256, 0, stream>>>(W1rt, Bt1u + 65536, 256, 256, flag);
  k_tpose<<<256, 256, 0, stream>>>(W1rb, Bt1i, 256, 256, flag);
  k_tpose<<<128, 256, 0, stream>>>(W2f, Bt2u, 256, 128, flag);
  k_tpose<<<128, 256, 0, stream>>>(W2rt, Bt2u + 32768, 256, 128, flag);
  k_tpose<<<128, 256, 0, stream>>>(W2rb, Bt2i, 256, 128, flag);

  // layer 1 GEMMs (rsqrt(out_deg) row scale commutes with @W; applied in epilogue)
  k_gemm<<<dim3(391, 4), 256, 0, stream>>>(x_user, Bt1u, featA, 50000, 512,
                                           R + 150000, R + 200000, 256, flag);
  k_gemm<<<dim3(391, 2), 256, 0, stream>>>(x_item, Bt1i, featB, 50000, 256,
                                           R + 250000, R + 250000, 256, flag);
  // layer 1 aggregation (bf16 stores into ws)
  k_spmm2<4, true><<<50000, 64, 0, stream>>>(featA, 512, 0, featB, 256, 0, csr, offs, 0, 50000,
                                             R, R + 50000, BF + 0, BF + 256,
                                             h_u, 0, 256, nullptr);
  k_spmm1<4, true><<<50000, 64, 0, stream>>>(featA, 512, 256, csr, offs, 100000,
                                             R + 100000, BF + 512,
                                             h_i, 0, 256, nullptr);
  // layer 2 GEMMs (A = bf16 ws buffers -> flagp=nullptr)
  k_gemm<<<dim3(391, 2), 256, 0, stream>>>(h_u, Bt2u, featA, 50000, 256,
                                           R + 150000, R + 200000, 128, nullptr);
  k_gemm<<<dim3(391, 1), 256, 0, stream>>>(h_i, Bt2i, feat2rb, 50000, 128,
                                           R + 250000, R + 250000, 128, nullptr);
  // layer 2 aggregation -> d_out, store dtype per flag
  k_spmm2<2, false><<<50000, 64, 0, stream>>>(featA, 256, 0, feat2rb, 128, 0, csr, offs, 0, 50000,
                                              R, R + 50000, BF + 768, BF + 1024,
                                              d_out, 0, 128, flag);
  k_spmm1<2, false><<<50000, 64, 0, stream>>>(featA, 256, 128, csr, offs, 100000,
                                              R + 100000, BF + 1280,
                                              d_out, (size_t)50000 * 128, 128, flag);
}

// Round 4
// 947.840 us; speedup vs baseline: 1.3640x; 1.3640x over previous
//
#include <hip/hip_runtime.h>

typedef unsigned short u16;
typedef __bf16 bf16x8 __attribute__((ext_vector_type(8)));
typedef float floatx4 __attribute__((ext_vector_type(4)));

#define NE 800000
#define NN 50000

__device__ __forceinline__ float b2f(unsigned u) { return __uint_as_float(u << 16); }
__device__ __forceinline__ u16 f2b(float f) {
  unsigned x = __float_as_uint(f);
  x += 0x7fffu + ((x >> 16) & 1u);
  return (u16)(x >> 16);
}

// ---------------- preprocessing ----------------
// DI layout (ints, later rsqrt floats in place):
// [0)=in_follows(user) [50000)=in_ratedby(user) [100000)=in_rates(item)
// [150000)=out_follows(user) [200000)=out_rates(user) [250000)=out_ratedby(item)
__global__ void k_degrees(const int* __restrict__ s0, const int* __restrict__ d0,
                          const int* __restrict__ s1, const int* __restrict__ d1,
                          const int* __restrict__ s2, const int* __restrict__ d2,
                          int* __restrict__ DI) {
  int t = blockIdx.x * 256 + threadIdx.x;
  if (t < NE) {
    atomicAdd(&DI[d0[t]], 1);
    atomicAdd(&DI[150000 + s0[t]], 1);
  } else if (t < 2 * NE) {
    int e = t - NE;
    atomicAdd(&DI[50000 + d1[e]], 1);
    atomicAdd(&DI[250000 + s1[e]], 1);
  } else if (t < 3 * NE) {
    int e = t - 2 * NE;
    atomicAdd(&DI[100000 + d2[e]], 1);
    atomicAdd(&DI[200000 + s2[e]], 1);
  }
}

// parallel exclusive scan over 150000 counts -> offs[0..150000]
__global__ __launch_bounds__(1024) void k_scan1(const int* __restrict__ cnt,
                                                int* __restrict__ offs,
                                                int* __restrict__ partials) {
  __shared__ int tmp[1024];
  int t = threadIdx.x, i = blockIdx.x * 1024 + t;
  int c = (i < 150000) ? cnt[i] : 0;
  tmp[t] = c; __syncthreads();
  for (int off = 1; off < 1024; off <<= 1) {
    int v = (t >= off) ? tmp[t - off] : 0;
    __syncthreads();
    tmp[t] += v;
    __syncthreads();
  }
  if (i <= 150000) offs[i] = tmp[t] - c;    // block-local exclusive
  if (t == 1023) partials[blockIdx.x] = tmp[1023];
}

__global__ __launch_bounds__(256) void k_scan2(int* __restrict__ partials) {
  __shared__ int tmp[256];
  int t = threadIdx.x;
  int c = (t < 147) ? partials[t] : 0;
  tmp[t] = c; __syncthreads();
  for (int off = 1; off < 256; off <<= 1) {
    int v = (t >= off) ? tmp[t - off] : 0;
    __syncthreads();
    tmp[t] += v;
    __syncthreads();
  }
  if (t < 147) partials[t] = tmp[t] - c;    // exclusive
}

__global__ __launch_bounds__(1024) void k_scan3(int* __restrict__ offs,
                                                const int* __restrict__ partials) {
  int i = blockIdx.x * 1024 + threadIdx.x;
  if (i <= 150000) offs[i] += partials[blockIdx.x];
}

__global__ void k_rsq(int* __restrict__ DI, int n) {
  int i = blockIdx.x * 256 + threadIdx.x;
  if (i < n) {
    float v = (float)DI[i];
    ((float*)DI)[i] = rsqrtf(fmaxf(v, 1.f));
  }
}

__global__ void k_scatter(const int* __restrict__ src, const int* __restrict__ dst,
                          const int* __restrict__ offsR, int* __restrict__ curR,
                          int* __restrict__ csr) {
  int e = blockIdx.x * 256 + threadIdx.x;
  if (e < NE) {
    int d = dst[e];
    int pos = atomicAdd(&curR[d], 1);
    csr[offsR[d] + pos] = src[e];
  }
}

// dst[n*K+k] = f2b(src[k*N+n]); src fp32 [K,N] row-major
__global__ void k_tpose(const float* __restrict__ src, u16* __restrict__ dst, int K, int N) {
  int i = blockIdx.x * 256 + threadIdx.x;
  if (i < K * N) {
    int n = i / K, k = i - n * K;
    dst[i] = f2b(src[k * N + n]);
  }
}

// ---------------- GEMM: C[M,Ntot] = A[M,256] @ Bt[Ntot,256]^T, epilogue row-scale ----------------
// A fp32 (AF32) or bf16. Bt/C bf16. fp32 MFMA accumulate.
template <bool AF32>
__global__ __launch_bounds__(256) void k_gemm(
    const void* __restrict__ A, const u16* __restrict__ Bt, u16* __restrict__ C,
    int M, int Ntot, const float* __restrict__ rs0, const float* __restrict__ rs1, int splitN) {
  __shared__ alignas(16) u16 As[128 * 64];
  __shared__ alignas(16) u16 Bs[128 * 64];
  const int tid = threadIdx.x;
  const int mBase = blockIdx.x * 128;
  const int nBase = blockIdx.y * 128;
  const int w = tid >> 6, lane = tid & 63;
  const int wm = w & 1, wn = w >> 1;
  const int lr = lane & 15, quad = lane >> 4;
  floatx4 acc[4][4] = {};
  for (int kb = 0; kb < 256; kb += 64) {
    uint4 va[4], vb[4];
#pragma unroll
    for (int c = 0; c < 4; ++c) {
      int idx = c * 256 + tid;       // 16B(bf16) chunk id; tile 128 rows x 64 cols
      int row = idx >> 3;
      int col8 = (idx & 7) * 8;
      int gr = mBase + row; if (gr > M - 1) gr = M - 1;   // clamp; masked at store
      if constexpr (AF32) {
        const float* ap = (const float*)A + (size_t)gr * 256 + kb + col8;
        float4 f0 = *(const float4*)ap;
        float4 f1 = *(const float4*)(ap + 4);
        va[c] = make_uint4(
            (unsigned)f2b(f0.x) | ((unsigned)f2b(f0.y) << 16),
            (unsigned)f2b(f0.z) | ((unsigned)f2b(f0.w) << 16),
            (unsigned)f2b(f1.x) | ((unsigned)f2b(f1.y) << 16),
            (unsigned)f2b(f1.z) | ((unsigned)f2b(f1.w) << 16));
      } else {
        va[c] = *(const uint4*)((const u16*)A + (size_t)gr * 256 + kb + col8);
      }
      vb[c] = *(const uint4*)(Bt + (size_t)(nBase + row) * 256 + kb + col8);
    }
#pragma unroll
    for (int c = 0; c < 4; ++c) {
      int idx = c * 256 + tid;
      *(uint4*)(&As[idx * 8]) = va[c];
      *(uint4*)(&Bs[idx * 8]) = vb[c];
    }
    __syncthreads();
#pragma unroll
    for (int ks = 0; ks < 2; ++ks) {
      bf16x8 fa[4], fb[4];
#pragma unroll
      for (int m = 0; m < 4; ++m)
        fa[m] = *(const bf16x8*)(&As[(wm * 64 + m * 16 + lr) * 64 + ks * 32 + quad * 8]);
#pragma unroll
      for (int n = 0; n < 4; ++n)
        fb[n] = *(const bf16x8*)(&Bs[(wn * 64 + n * 16 + lr) * 64 + ks * 32 + quad * 8]);
#pragma unroll
      for (int m = 0; m < 4; ++m)
#pragma unroll
        for (int n = 0; n < 4; ++n)
          acc[m][n] = __builtin_amdgcn_mfma_f32_16x16x32_bf16(fa[m], fb[n], acc[m][n], 0, 0, 0);
    }
    __syncthreads();
  }
  // C/D layout: col = lane&15, row = quad*4 + reg  [m89-verified]
#pragma unroll
  for (int n = 0; n < 4; ++n) {
    int cg = nBase + wn * 64 + n * 16 + lr;
    const float* rs = (cg < splitN) ? rs0 : rs1;
#pragma unroll
    for (int m = 0; m < 4; ++m) {
      int rb_ = mBase + wm * 64 + m * 16 + quad * 4;
#pragma unroll
      for (int r = 0; r < 4; ++r) {
        int rg = rb_ + r;
        if (rg < M) C[(size_t)rg * Ntot + cg] = f2b(acc[m][n][r] * rs[rg]);
      }
    }
  }
}

// ---------------- SpMM (CSR by dst), fp32 accumulate, edge-unroll x2 ----------------
template <int VEC>
__device__ __forceinline__ void addv(float* acc, const u16* p) {
  if constexpr (VEC == 4) {
    uint2 v = *(const uint2*)p;
    acc[0] += b2f(v.x & 0xffffu); acc[1] += b2f(v.x >> 16);
    acc[2] += b2f(v.y & 0xffffu); acc[3] += b2f(v.y >> 16);
  } else {
    unsigned v = *(const unsigned*)p;
    acc[0] += b2f(v & 0xffffu); acc[1] += b2f(v >> 16);
  }
}

__device__ __forceinline__ int clampi(int s) {
  return (s < 0) ? 0 : (s > NN - 1 ? NN - 1 : s);
}

template <int VEC>
__device__ __forceinline__ void gather(float* acc0, float* acc1, const u16* f, int stride,
                                       int off, const int* __restrict__ csr, int st, int en,
                                       int lane) {
  int e = st;
  for (; e + 1 < en; e += 2) {
    int i0 = clampi(csr[e]), i1 = clampi(csr[e + 1]);
    addv<VEC>(acc0, f + (size_t)i0 * stride + off + lane * VEC);
    addv<VEC>(acc1, f + (size_t)i1 * stride + off + lane * VEC);
  }
  if (e < en) addv<VEC>(acc0, f + (size_t)clampi(csr[e]) * stride + off + lane * VEC);
}

// two relations: out = maybeRELU( 0.5*(aggA*rsA + bA + aggB*rsB + bB) )
template <int VEC, bool RELU, bool OUT32>
__global__ __launch_bounds__(64) void k_spmm2(
    const u16* __restrict__ fA, int sA, int oA,
    const u16* __restrict__ fB, int sB, int oB,
    const int* __restrict__ csr, const int* __restrict__ offs, int baseA, int baseB,
    const float* __restrict__ rsA, const float* __restrict__ rsB,
    const float* __restrict__ bA, const float* __restrict__ bB,
    void* __restrict__ outv, size_t outBase, int sOut) {
  int d = blockIdx.x, lane = threadIdx.x;
  float a0[VEC] = {}, a1[VEC] = {}, b0[VEC] = {}, b1[VEC] = {};
  gather<VEC>(a0, a1, fA, sA, oA, csr, offs[baseA + d], offs[baseA + d + 1], lane);
  gather<VEC>(b0, b1, fB, sB, oB, csr, offs[baseB + d], offs[baseB + d + 1], lane);
  float ra = rsA[d], rb = rsB[d];
  size_t o = outBase + (size_t)d * sOut + lane * VEC;
#pragma unroll
  for (int v = 0; v < VEC; ++v) {
    float x = 0.5f * ((a0[v] + a1[v]) * ra + bA[lane * VEC + v]
                      + (b0[v] + b1[v]) * rb + bB[lane * VEC + v]);
    if (RELU) x = fmaxf(x, 0.f);
    if (OUT32) ((float*)outv)[o + v] = x;
    else       ((u16*)outv)[o + v] = f2b(x);
  }
}

// single relation
template <int VEC, bool RELU, bool OUT32>
__global__ __launch_bounds__(64) void k_spmm1(
    const u16* __restrict__ fA, int sA, int oA,
    const int* __restrict__ csr, const int* __restrict__ offs, int baseA,
    const float* __restrict__ rsA, const float* __restrict__ bA,
    void* __restrict__ outv, size_t outBase, int sOut) {
  int d = blockIdx.x, lane = threadIdx.x;
  float a0[VEC] = {}, a1[VEC] = {};
  gather<VEC>(a0, a1, fA, sA, oA, csr, offs[baseA + d], offs[baseA + d + 1], lane);
  float ra = rsA[d];
  size_t o = outBase + (size_t)d * sOut + lane * VEC;
#pragma unroll
  for (int v = 0; v < VEC; ++v) {
    float x = (a0[v] + a1[v]) * ra + bA[lane * VEC + v];
    if (RELU) x = fmaxf(x, 0.f);
    if (OUT32) ((float*)outv)[o + v] = x;
    else       ((u16*)outv)[o + v] = f2b(x);
  }
}

extern "C" void kernel_launch(void* const* d_in, const int* in_sizes, int n_in,
                              void* d_out, int out_size, void* d_ws, size_t ws_size,
                              hipStream_t stream) {
  (void)in_sizes; (void)n_in; (void)out_size;
  const float* x_user = (const float*)d_in[0];
  const float* x_item = (const float*)d_in[1];
  const float* W1f  = (const float*)d_in[2];  const float* b1f  = (const float*)d_in[3];
  const float* W1rt = (const float*)d_in[4];  const float* b1rt = (const float*)d_in[5];
  const float* W1rb = (const float*)d_in[6];  const float* b1rb = (const float*)d_in[7];
  const float* W2f  = (const float*)d_in[8];  const float* b2fo = (const float*)d_in[9];
  const float* W2rt = (const float*)d_in[10]; const float* b2rt = (const float*)d_in[11];
  const float* W2rb = (const float*)d_in[12]; const float* b2rb = (const float*)d_in[13];
  const int* srcF  = (const int*)d_in[14]; const int* dstF  = (const int*)d_in[15];
  const int* srcR  = (const int*)d_in[16]; const int* dstR  = (const int*)d_in[17];
  const int* srcRB = (const int*)d_in[18]; const int* dstRB = (const int*)d_in[19];

  // ---- workspace layout (bytes) — identical footprint to round 3 (ws_size-proven) ----
  // DI/R   : [0, 1200000)           300000 i32 -> f32 in place
  // cursor : [1200000, 1800000)     150000 i32
  // offs   : [1800064, 2400068)     150001 i32
  // csr    : [2400128, 12000128)    2400000 i32  (first 588 B double as scan partials)
  // Bt1u/Bt1i/Bt2u/Bt2i bf16        [12000128, 12589952)
  // featA  : [12589952, 63789952)   [50000,512] bf16 (layer2: [50000,256] + feat2rb)
  // featB  : [63789952, 89389952)   [50000,256]
  // h_u    : [89389952, 114989952)  [50000,256]
  if (ws_size < 114989952u) return;

  char* ws = (char*)d_ws;
  int*   DI     = (int*)ws;
  float* R      = (float*)ws;
  int*   cursor = (int*)(ws + 1200000);
  int*   offs   = (int*)(ws + 1800064);
  int*   csr    = (int*)(ws + 2400128);
  int*   partials = csr;                    // free until scatters (stream-ordered)
  u16*   Bt1u   = (u16*)(ws + 12000128);
  u16*   Bt1i   = (u16*)(ws + 12262272);
  u16*   Bt2u   = (u16*)(ws + 12393344);
  u16*   Bt2i   = (u16*)(ws + 12524416);
  u16*   featA  = (u16*)(ws + 12589952);
  u16*   featB  = (u16*)(ws + 63789952);
  u16*   h_u    = (u16*)(ws + 89389952);
  u16*   h_i    = featB;
  u16*   feat2rb = featA + (size_t)50000 * 256;

  hipMemsetAsync(ws, 0, 1800000, stream);            // degrees + cursors
  k_degrees<<<(3 * NE + 255) / 256, 256, 0, stream>>>(srcF, dstF, srcRB, dstRB, srcR, dstR, DI);
  k_scan1<<<147, 1024, 0, stream>>>(DI, offs, partials);
  k_scan2<<<1, 256, 0, stream>>>(partials);
  k_scan3<<<147, 1024, 0, stream>>>(offs, partials);
  k_rsq<<<(300000 + 255) / 256, 256, 0, stream>>>(DI, 300000);
  k_scatter<<<(NE + 255) / 256, 256, 0, stream>>>(srcF, dstF, offs, cursor, csr);
  k_scatter<<<(NE + 255) / 256, 256, 0, stream>>>(srcRB, dstRB, offs + 50000, cursor + 50000, csr);
  k_scatter<<<(NE + 255) / 256, 256, 0, stream>>>(srcR, dstR, offs + 100000, cursor + 100000, csr);
  k_tpose<<<256, 256, 0, stream>>>(W1f, Bt1u, 256, 256);
  k_tpose<<<256, 256, 0, stream>>>(W1rt, Bt1u + 65536, 256, 256);
  k_tpose<<<256, 256, 0, stream>>>(W1rb, Bt1i, 256, 256);
  k_tpose<<<128, 256, 0, stream>>>(W2f, Bt2u, 256, 128);
  k_tpose<<<128, 256, 0, stream>>>(W2rt, Bt2u + 32768, 256, 128);
  k_tpose<<<128, 256, 0, stream>>>(W2rb, Bt2i, 256, 128);

  // layer 1 GEMMs (rsqrt(out_deg) row scale commutes with @W; applied in epilogue)
  k_gemm<true><<<dim3(391, 4), 256, 0, stream>>>(x_user, Bt1u, featA, 50000, 512,
                                                 R + 150000, R + 200000, 256);
  k_gemm<true><<<dim3(391, 2), 256, 0, stream>>>(x_item, Bt1i, featB, 50000, 256,
                                                 R + 250000, R + 250000, 256);
  // layer 1 aggregation (bf16 stores into ws)
  k_spmm2<4, true, false><<<50000, 64, 0, stream>>>(featA, 512, 0, featB, 256, 0,
                                                    csr, offs, 0, 50000,
                                                    R, R + 50000, b1f, b1rb, h_u, 0, 256);
  k_spmm1<4, true, false><<<50000, 64, 0, stream>>>(featA, 512, 256, csr, offs, 100000,
                                                    R + 100000, b1rt, h_i, 0, 256);
  // layer 2 GEMMs (A = bf16 ws buffers)
  k_gemm<false><<<dim3(391, 2), 256, 0, stream>>>(h_u, Bt2u, featA, 50000, 256,
                                                  R + 150000, R + 200000, 128);
  k_gemm<false><<<dim3(391, 1), 256, 0, stream>>>(h_i, Bt2i, feat2rb, 50000, 128,
                                                  R + 250000, R + 250000, 128);
  // layer 2 aggregation -> d_out (fp32)
  k_spmm2<2, false, true><<<50000, 64, 0, stream>>>(featA, 256, 0, feat2rb, 128, 0,
                                                    csr, offs, 0, 50000,
                                                    R, R + 50000, b2fo, b2rb, d_out, 0, 128);
  k_spmm1<2, false, true><<<50000, 64, 0, stream>>>(featA, 256, 128, csr, offs, 100000,
                                                    R + 100000, b2rt, d_out, (size_t)50000 * 128, 128);
}

// Round 5
// 757.682 us; speedup vs baseline: 1.7064x; 1.2510x over previous
//
#include <hip/hip_runtime.h>

typedef unsigned short u16;
typedef __bf16 bf16x8 __attribute__((ext_vector_type(8)));
typedef float floatx4 __attribute__((ext_vector_type(4)));

#define NE 800000
#define NN 50000
#define CHUNKS 32
#define CHUNK (NE / CHUNKS)   // 25000
#define WIN 25000             // histogram window per segment (2 windows per array)

__device__ __forceinline__ float b2f(unsigned u) { return __uint_as_float(u << 16); }
__device__ __forceinline__ u16 f2b(float f) {
  unsigned x = __float_as_uint(f);
  x += 0x7fffu + ((x >> 16) & 1u);
  return (u16)(x >> 16);
}

// ---------------- histogram degrees (LDS, atomic-free in HBM) ----------------
// segment g in [0,12): array a=g>>1, window r=g&1 covering idx in [r*WIN,(r+1)*WIN)
// arrays: 0=dstF 1=dstRB 2=dstR 3=srcF 4=srcR 5=srcRB  (matches DI layout below)
__global__ __launch_bounds__(256) void k_hist(
    const int* __restrict__ dF, const int* __restrict__ dRB, const int* __restrict__ dR,
    const int* __restrict__ sF, const int* __restrict__ sR, const int* __restrict__ sRB,
    u16* __restrict__ partial) {
  __shared__ unsigned h[WIN / 2];          // packed u16 pairs, 50 KB
  int c = blockIdx.x, g = blockIdx.y, t = threadIdx.x;
  int a = g >> 1, lo = (g & 1) * WIN;
  for (int i = t; i < WIN / 2; i += 256) h[i] = 0;
  __syncthreads();
  const int* idx = (a == 0) ? dF : (a == 1) ? dRB : (a == 2) ? dR
                 : (a == 3) ? sF : (a == 4) ? sR : sRB;
  int st = c * CHUNK, en = st + CHUNK;
  for (int e = st + t; e < en; e += 256) {
    unsigned u = (unsigned)(idx[e] - lo);
    if (u < (unsigned)WIN) atomicAdd(&h[u >> 1], 1u << ((u & 1) * 16));
  }
  __syncthreads();
  unsigned* po = (unsigned*)(partial + ((size_t)g * CHUNKS + c) * WIN);
  for (int i = t; i < WIN / 2; i += 256) po[i] = h[i];
}

// partials -> DI counts; byproduct: exclusive per-chunk cumsum for relations (g<6)
__global__ __launch_bounds__(256) void k_hreduce(const u16* __restrict__ partial,
                                                 u16* __restrict__ chunkcum,
                                                 int* __restrict__ DI) {
  int i = blockIdx.x * 256 + threadIdx.x;
  int g = blockIdx.y;
  if (i >= WIN) return;
  const u16* p = partial + (size_t)g * CHUNKS * WIN + i;
  u16* cc = chunkcum + (size_t)g * CHUNKS * WIN + i;   // only meaningful for g<6
  int run = 0;
#pragma unroll
  for (int c = 0; c < CHUNKS; ++c) {
    if (g < 6) cc[(size_t)c * WIN] = (u16)run;
    run += p[(size_t)c * WIN];
  }
  int a = g >> 1, r = g & 1;
  DI[a * NN + r * WIN + i] = run;
}

// parallel exclusive scan over 150000 counts -> offs[0..150000]
__global__ __launch_bounds__(1024) void k_scan1(const int* __restrict__ cnt,
                                                int* __restrict__ offs,
                                                int* __restrict__ partials) {
  __shared__ int tmp[1024];
  int t = threadIdx.x, i = blockIdx.x * 1024 + t;
  int c = (i < 150000) ? cnt[i] : 0;
  tmp[t] = c; __syncthreads();
  for (int off = 1; off < 1024; off <<= 1) {
    int v = (t >= off) ? tmp[t - off] : 0;
    __syncthreads();
    tmp[t] += v;
    __syncthreads();
  }
  if (i <= 150000) offs[i] = tmp[t] - c;
  if (t == 1023) partials[blockIdx.x] = tmp[1023];
}

__global__ __launch_bounds__(256) void k_scan2(int* __restrict__ partials) {
  __shared__ int tmp[256];
  int t = threadIdx.x;
  int c = (t < 147) ? partials[t] : 0;
  tmp[t] = c; __syncthreads();
  for (int off = 1; off < 256; off <<= 1) {
    int v = (t >= off) ? tmp[t - off] : 0;
    __syncthreads();
    tmp[t] += v;
    __syncthreads();
  }
  if (t < 147) partials[t] = tmp[t] - c;
}

__global__ __launch_bounds__(1024) void k_scan3(int* __restrict__ offs,
                                                const int* __restrict__ partials) {
  int i = blockIdx.x * 1024 + threadIdx.x;
  if (i <= 150000) offs[i] += partials[blockIdx.x];
}

__global__ void k_rsq(int* __restrict__ DI, int n) {
  int i = blockIdx.x * 256 + threadIdx.x;
  if (i < n) {
    float v = (float)DI[i];
    ((float*)DI)[i] = rsqrtf(fmaxf(v, 1.f));
  }
}

// CSR scatter, atomic-free: slot = offs[dst] + chunkcum[dst] + LDS-rank
__global__ __launch_bounds__(256) void k_scatlds(
    const int* __restrict__ sF, const int* __restrict__ dF,
    const int* __restrict__ sRB, const int* __restrict__ dRB,
    const int* __restrict__ sR, const int* __restrict__ dR,
    const int* __restrict__ offs, const u16* __restrict__ chunkcum,
    int* __restrict__ csr) {
  __shared__ unsigned h[WIN / 2];          // rank counters, 50 KB
  int c = blockIdx.x, g = blockIdx.y, t = threadIdx.x;
  int a = g >> 1, lo = (g & 1) * WIN;
  for (int i = t; i < WIN / 2; i += 256) h[i] = 0;
  __syncthreads();
  const int* s = (a == 0) ? sF : (a == 1) ? sRB : sR;
  const int* d = (a == 0) ? dF : (a == 1) ? dRB : dR;
  int base = a * NN;
  const u16* cc = chunkcum + ((size_t)g * CHUNKS + c) * WIN;
  int st = c * CHUNK, en = st + CHUNK;
  for (int e = st + t; e < en; e += 256) {
    int dd = d[e];
    unsigned u = (unsigned)(dd - lo);
    if (u < (unsigned)WIN) {
      unsigned sh = (u & 1) * 16;
      unsigned old = atomicAdd(&h[u >> 1], 1u << sh);
      int r = (int)((old >> sh) & 0xffffu);
      csr[offs[base + dd] + (int)cc[u] + r] = s[e];
    }
  }
}

// 6 weight transposes fused: dst[n*256+k] = f2b(src[k*N+n]), K=256 rows
__global__ void k_tpose6(const float* __restrict__ W1f, const float* __restrict__ W1rt,
                         const float* __restrict__ W1rb, const float* __restrict__ W2f,
                         const float* __restrict__ W2rt, const float* __restrict__ W2rb,
                         u16* __restrict__ Bt1u, u16* __restrict__ Bt1i,
                         u16* __restrict__ Bt2u, u16* __restrict__ Bt2i) {
  int a = blockIdx.y;
  const float* src; u16* dst; int N;
  switch (a) {
    case 0: src = W1f;  dst = Bt1u;         N = 256; break;
    case 1: src = W1rt; dst = Bt1u + 65536; N = 256; break;
    case 2: src = W1rb; dst = Bt1i;         N = 256; break;
    case 3: src = W2f;  dst = Bt2u;         N = 128; break;
    case 4: src = W2rt; dst = Bt2u + 32768; N = 128; break;
    default: src = W2rb; dst = Bt2i;        N = 128; break;
  }
  int i = blockIdx.x * 256 + threadIdx.x;
  if (i < 256 * N) {
    int n = i >> 8, k = i & 255;
    dst[i] = f2b(src[(size_t)k * N + n]);
  }
}

// ---------------- GEMM: C[M,Ntot] = A[M,256] @ Bt[Ntot,256]^T, epilogue row-scale ----------------
template <bool AF32>
__global__ __launch_bounds__(256) void k_gemm(
    const void* __restrict__ A, const u16* __restrict__ Bt, u16* __restrict__ C,
    int M, int Ntot, const float* __restrict__ rs0, const float* __restrict__ rs1, int splitN) {
  __shared__ alignas(16) u16 As[128 * 64];
  __shared__ alignas(16) u16 Bs[128 * 64];
  const int tid = threadIdx.x;
  const int mBase = blockIdx.x * 128;
  const int nBase = blockIdx.y * 128;
  const int w = tid >> 6, lane = tid & 63;
  const int wm = w & 1, wn = w >> 1;
  const int lr = lane & 15, quad = lane >> 4;
  floatx4 acc[4][4] = {};
  for (int kb = 0; kb < 256; kb += 64) {
    uint4 va[4], vb[4];
#pragma unroll
    for (int c = 0; c < 4; ++c) {
      int idx = c * 256 + tid;
      int row = idx >> 3;
      int col8 = (idx & 7) * 8;
      int gr = mBase + row; if (gr > M - 1) gr = M - 1;
      if constexpr (AF32) {
        const float* ap = (const float*)A + (size_t)gr * 256 + kb + col8;
        float4 f0 = *(const float4*)ap;
        float4 f1 = *(const float4*)(ap + 4);
        va[c] = make_uint4(
            (unsigned)f2b(f0.x) | ((unsigned)f2b(f0.y) << 16),
            (unsigned)f2b(f0.z) | ((unsigned)f2b(f0.w) << 16),
            (unsigned)f2b(f1.x) | ((unsigned)f2b(f1.y) << 16),
            (unsigned)f2b(f1.z) | ((unsigned)f2b(f1.w) << 16));
      } else {
        va[c] = *(const uint4*)((const u16*)A + (size_t)gr * 256 + kb + col8);
      }
      vb[c] = *(const uint4*)(Bt + (size_t)(nBase + row) * 256 + kb + col8);
    }
#pragma unroll
    for (int c = 0; c < 4; ++c) {
      int idx = c * 256 + tid;
      *(uint4*)(&As[idx * 8]) = va[c];
      *(uint4*)(&Bs[idx * 8]) = vb[c];
    }
    __syncthreads();
#pragma unroll
    for (int ks = 0; ks < 2; ++ks) {
      bf16x8 fa[4], fb[4];
#pragma unroll
      for (int m = 0; m < 4; ++m)
        fa[m] = *(const bf16x8*)(&As[(wm * 64 + m * 16 + lr) * 64 + ks * 32 + quad * 8]);
#pragma unroll
      for (int n = 0; n < 4; ++n)
        fb[n] = *(const bf16x8*)(&Bs[(wn * 64 + n * 16 + lr) * 64 + ks * 32 + quad * 8]);
#pragma unroll
      for (int m = 0; m < 4; ++m)
#pragma unroll
        for (int n = 0; n < 4; ++n)
          acc[m][n] = __builtin_amdgcn_mfma_f32_16x16x32_bf16(fa[m], fb[n], acc[m][n], 0, 0, 0);
    }
    __syncthreads();
  }
#pragma unroll
  for (int n = 0; n < 4; ++n) {
    int cg = nBase + wn * 64 + n * 16 + lr;
    const float* rs = (cg < splitN) ? rs0 : rs1;
#pragma unroll
    for (int m = 0; m < 4; ++m) {
      int rb_ = mBase + wm * 64 + m * 16 + quad * 4;
#pragma unroll
      for (int r = 0; r < 4; ++r) {
        int rg = rb_ + r;
        if (rg < M) C[(size_t)rg * Ntot + cg] = f2b(acc[m][n][r] * rs[rg]);
      }
    }
  }
}

// ---------------- SpMM (CSR by dst), fp32 accumulate, edge-unroll x2 ----------------
template <int VEC>
__device__ __forceinline__ void addv(float* acc, const u16* p) {
  if constexpr (VEC == 4) {
    uint2 v = *(const uint2*)p;
    acc[0] += b2f(v.x & 0xffffu); acc[1] += b2f(v.x >> 16);
    acc[2] += b2f(v.y & 0xffffu); acc[3] += b2f(v.y >> 16);
  } else {
    unsigned v = *(const unsigned*)p;
    acc[0] += b2f(v & 0xffffu); acc[1] += b2f(v >> 16);
  }
}

__device__ __forceinline__ int clampi(int s) {
  return (s < 0) ? 0 : (s > NN - 1 ? NN - 1 : s);
}

template <int VEC>
__device__ __forceinline__ void gather(float* acc0, float* acc1, const u16* f, int stride,
                                       int off, const int* __restrict__ csr, int st, int en,
                                       int lane) {
  int e = st;
  for (; e + 1 < en; e += 2) {
    int i0 = clampi(csr[e]), i1 = clampi(csr[e + 1]);
    addv<VEC>(acc0, f + (size_t)i0 * stride + off + lane * VEC);
    addv<VEC>(acc1, f + (size_t)i1 * stride + off + lane * VEC);
  }
  if (e < en) addv<VEC>(acc0, f + (size_t)clampi(csr[e]) * stride + off + lane * VEC);
}

template <int VEC, bool RELU, bool OUT32>
__global__ __launch_bounds__(64) void k_spmm2(
    const u16* __restrict__ fA, int sA, int oA,
    const u16* __restrict__ fB, int sB, int oB,
    const int* __restrict__ csr, const int* __restrict__ offs, int baseA, int baseB,
    const float* __restrict__ rsA, const float* __restrict__ rsB,
    const float* __restrict__ bA, const float* __restrict__ bB,
    void* __restrict__ outv, size_t outBase, int sOut) {
  int d = blockIdx.x, lane = threadIdx.x;
  float a0[VEC] = {}, a1[VEC] = {}, b0[VEC] = {}, b1[VEC] = {};
  gather<VEC>(a0, a1, fA, sA, oA, csr, offs[baseA + d], offs[baseA + d + 1], lane);
  gather<VEC>(b0, b1, fB, sB, oB, csr, offs[baseB + d], offs[baseB + d + 1], lane);
  float ra = rsA[d], rb = rsB[d];
  size_t o = outBase + (size_t)d * sOut + lane * VEC;
#pragma unroll
  for (int v = 0; v < VEC; ++v) {
    float x = 0.5f * ((a0[v] + a1[v]) * ra + bA[lane * VEC + v]
                      + (b0[v] + b1[v]) * rb + bB[lane * VEC + v]);
    if (RELU) x = fmaxf(x, 0.f);
    if (OUT32) ((float*)outv)[o + v] = x;
    else       ((u16*)outv)[o + v] = f2b(x);
  }
}

template <int VEC, bool RELU, bool OUT32>
__global__ __launch_bounds__(64) void k_spmm1(
    const u16* __restrict__ fA, int sA, int oA,
    const int* __restrict__ csr, const int* __restrict__ offs, int baseA,
    const float* __restrict__ rsA, const float* __restrict__ bA,
    void* __restrict__ outv, size_t outBase, int sOut) {
  int d = blockIdx.x, lane = threadIdx.x;
  float a0[VEC] = {}, a1[VEC] = {};
  gather<VEC>(a0, a1, fA, sA, oA, csr, offs[baseA + d], offs[baseA + d + 1], lane);
  float ra = rsA[d];
  size_t o = outBase + (size_t)d * sOut + lane * VEC;
#pragma unroll
  for (int v = 0; v < VEC; ++v) {
    float x = (a0[v] + a1[v]) * ra + bA[lane * VEC + v];
    if (RELU) x = fmaxf(x, 0.f);
    if (OUT32) ((float*)outv)[o + v] = x;
    else       ((u16*)outv)[o + v] = f2b(x);
  }
}

extern "C" void kernel_launch(void* const* d_in, const int* in_sizes, int n_in,
                              void* d_out, int out_size, void* d_ws, size_t ws_size,
                              hipStream_t stream) {
  (void)in_sizes; (void)n_in; (void)out_size;
  const float* x_user = (const float*)d_in[0];
  const float* x_item = (const float*)d_in[1];
  const float* W1f  = (const float*)d_in[2];  const float* b1f  = (const float*)d_in[3];
  const float* W1rt = (const float*)d_in[4];  const float* b1rt = (const float*)d_in[5];
  const float* W1rb = (const float*)d_in[6];  const float* b1rb = (const float*)d_in[7];
  const float* W2f  = (const float*)d_in[8];  const float* b2fo = (const float*)d_in[9];
  const float* W2rt = (const float*)d_in[10]; const float* b2rt = (const float*)d_in[11];
  const float* W2rb = (const float*)d_in[12]; const float* b2rb = (const float*)d_in[13];
  const int* srcF  = (const int*)d_in[14]; const int* dstF  = (const int*)d_in[15];
  const int* srcR  = (const int*)d_in[16]; const int* dstR  = (const int*)d_in[17];
  const int* srcRB = (const int*)d_in[18]; const int* dstRB = (const int*)d_in[19];

  // ---- workspace layout (bytes) ----
  // DI/R   : [0, 1200000)           300000 i32 -> f32 in place
  // offs   : [1800064, 2400068)     150001 i32
  // csr    : [2400128, 12000128)    2400000 i32  (first 588 B double as scan partials)
  // Bt1u/Bt1i/Bt2u/Bt2i bf16        [12000128, 12589952)
  // featA  : [12589952, 63789952)   [50000,512] bf16
  //          scratch (pre-GEMM): partial u16 12*32*25000 @featA+0 (19.2MB),
  //                              chunkcum u16 6*32*25000 @featA+19.2MB (9.6MB)
  // featB  : [63789952, 89389952)   [50000,256]
  // h_u    : [89389952, 114989952)  [50000,256]
  if (ws_size < 114989952u) return;

  char* ws = (char*)d_ws;
  int*   DI     = (int*)ws;
  float* R      = (float*)ws;
  int*   offs   = (int*)(ws + 1800064);
  int*   csr    = (int*)(ws + 2400128);
  int*   partials = csr;                    // scan scratch, free until k_scatlds
  u16*   Bt1u   = (u16*)(ws + 12000128);
  u16*   Bt1i   = (u16*)(ws + 12262272);
  u16*   Bt2u   = (u16*)(ws + 12393344);
  u16*   Bt2i   = (u16*)(ws + 12524416);
  u16*   featA  = (u16*)(ws + 12589952);
  u16*   featB  = (u16*)(ws + 63789952);
  u16*   h_u    = (u16*)(ws + 89389952);
  u16*   h_i    = featB;
  u16*   feat2rb = featA + (size_t)50000 * 256;
  u16*   hpart  = featA;                    // 12*32*25000 u16, dead before GEMM1
  u16*   chunkcum = featA + (size_t)12 * CHUNKS * WIN;  // 6*32*25000 u16

  k_hist<<<dim3(CHUNKS, 12), 256, 0, stream>>>(dstF, dstRB, dstR, srcF, srcR, srcRB, hpart);
  k_hreduce<<<dim3(98, 12), 256, 0, stream>>>(hpart, chunkcum, DI);
  k_scan1<<<147, 1024, 0, stream>>>(DI, offs, partials);
  k_scan2<<<1, 256, 0, stream>>>(partials);
  k_scan3<<<147, 1024, 0, stream>>>(offs, partials);
  k_rsq<<<(300000 + 255) / 256, 256, 0, stream>>>(DI, 300000);
  k_scatlds<<<dim3(CHUNKS, 6), 256, 0, stream>>>(srcF, dstF, srcRB, dstRB, srcR, dstR,
                                                 offs, chunkcum, csr);
  k_tpose6<<<dim3(256, 6), 256, 0, stream>>>(W1f, W1rt, W1rb, W2f, W2rt, W2rb,
                                             Bt1u, Bt1i, Bt2u, Bt2i);

  // layer 1 GEMMs (rsqrt(out_deg) row scale commutes with @W; applied in epilogue)
  k_gemm<true><<<dim3(391, 4), 256, 0, stream>>>(x_user, Bt1u, featA, 50000, 512,
                                                 R + 150000, R + 200000, 256);
  k_gemm<true><<<dim3(391, 2), 256, 0, stream>>>(x_item, Bt1i, featB, 50000, 256,
                                                 R + 250000, R + 250000, 256);
  // layer 1 aggregation (bf16 stores into ws)
  k_spmm2<4, true, false><<<50000, 64, 0, stream>>>(featA, 512, 0, featB, 256, 0,
                                                    csr, offs, 0, 50000,
                                                    R, R + 50000, b1f, b1rb, h_u, 0, 256);
  k_spmm1<4, true, false><<<50000, 64, 0, stream>>>(featA, 512, 256, csr, offs, 100000,
                                                    R + 100000, b1rt, h_i, 0, 256);
  // layer 2 GEMMs (A = bf16 ws buffers)
  k_gemm<false><<<dim3(391, 2), 256, 0, stream>>>(h_u, Bt2u, featA, 50000, 256,
                                                  R + 150000, R + 200000, 128);
  k_gemm<false><<<dim3(391, 1), 256, 0, stream>>>(h_i, Bt2i, feat2rb, 50000, 128,
                                                  R + 250000, R + 250000, 128);
  // layer 2 aggregation -> d_out (fp32)
  k_spmm2<2, false, true><<<50000, 64, 0, stream>>>(featA, 256, 0, feat2rb, 128, 0,
                                                    csr, offs, 0, 50000,
                                                    R, R + 50000, b2fo, b2rb, d_out, 0, 128);
  k_spmm1<2, false, true><<<50000, 64, 0, stream>>>(featA, 256, 128, csr, offs, 100000,
                                                    R + 100000, b2rt, d_out, (size_t)50000 * 128, 128);
}